// Round 1
// baseline (183.324 us; speedup 1.0000x reference)
//
#include <hip/hip_runtime.h>
#include <hip/hip_bf16.h>

// DynamicConv1D fused kernel for MI355X (gfx950).
//
// Reference: dw = conv1d(x, W) + b  -> [B, O*I*K, T]
//            sm = softmax(dw/sqrt(7), axis=K)
//            y[b,o,t] = sum_{i,k} x[b,i,t+k-3] * sm[b,o,i,k,t]
//
// Plan:
//  prep1 (wprep): permute W -> Wp bf16 [ch][j][r'][c], ch=chunk of 112 rows
//                 (16 (o,i) pairs x 7 taps), r' = k*16 + p  (tap-major!),
//                 contraction dim reordered to (j outer, c inner).
//                 Also bias bp[ch*112 + k*16 + p].
//  prep2 (xprep): transpose x -> xT bf16 [b][t][c].
//  main: 256 blocks = (b:4) x (t-tile:32, BLK_T=128) x (o-half:2).
//        8 waves = (stream wo:2 [o parity]) x (col quarter wt:4, 32 cols each).
//        Per chunk: 7 j-steps, each: stage next 7KB W j-slice (global_load_lds,
//        double buffered) + 7 M-tiles x 2 col-tiles MFMA 16x16x32 bf16.
//        acc[m=k][ct] init = bias. After 7 j-steps: softmax over m (lane-local!)
//        + einsum contribution into yacc; per o (2 chunks) shfl-reduce over
//        lane groups and store y.

typedef unsigned short u16;
typedef unsigned int u32;
typedef __attribute__((ext_vector_type(8))) short short8;
typedef __attribute__((ext_vector_type(4))) float f32x4;

#define IN_CH 32
#define OUT_CH 32
#define KW 7
#define TSZ 4096
#define BSZ 4
#define CONTR 224          // IN_CH*KW
#define NROWS 7168         // OUT_CH*IN_CH*KW
#define BLK_T 128
#define XS_STRIDE 38       // u16 per xs row (76B; odd dword count -> spread banks)
#define XS_ROWS (BLK_T + 6)
#define SLICE_U16 3584     // 112 rows * 32 c
#define CEXP2 0.5452875f   // log2(e)/sqrt(7)

__device__ __forceinline__ u32 f2bf(float v) {   // f32 -> bf16 bits (RNE)
    u32 b = __float_as_uint(v);
    return (b + 0x7fffu + ((b >> 16) & 1u)) >> 16;
}

__device__ __forceinline__ void glds16(const u16* g, u16* l) {
    // 16B per lane, LDS dest = l + lane*16 (wave-uniform base, linear)
    __builtin_amdgcn_global_load_lds((__attribute__((address_space(1))) void*)g,
                                     (__attribute__((address_space(3))) void*)l,
                                     16, 0, 0);
}

// ---------------- prep 1: W permute + bf16, bias permute -------------------
__global__ __launch_bounds__(256)
void wprep(const float* __restrict__ W, const float* __restrict__ bias,
           u16* __restrict__ Wp, float* __restrict__ bp) {
    int idx = blockIdx.x * 256 + threadIdx.x;
    if (idx < NROWS * CONTR) {
        int c  = idx & 31;
        int t1 = idx >> 5;          // (ch*7+j)*112 + r'
        int rp = t1 % 112;
        int t2 = t1 / 112;          // ch*7 + j
        int j  = t2 % 7;
        int ch = t2 / 7;
        int k  = rp >> 4;
        int p  = rp & 15;
        int gp = ch * 16 + p;       // global pair index = o*32 + i
        int o  = gp >> 5;
        int i  = gp & 31;
        int grow = (o * IN_CH + i) * KW + k;
        float v = W[(size_t)grow * CONTR + c * KW + j];
        Wp[idx] = (u16)f2bf(v);
    }
    if (idx < NROWS) {
        int rp = idx % 112;
        int ch = idx / 112;
        int k = rp >> 4, p = rp & 15;
        int gp = ch * 16 + p;
        int o = gp >> 5, i = gp & 31;
        bp[idx] = bias[(o * IN_CH + i) * KW + k];
    }
}

// ---------------- prep 2: x -> xT bf16 [b][t][c] ---------------------------
__global__ __launch_bounds__(256)
void xprep(const float* __restrict__ x, u16* __restrict__ xT) {
    int bid = blockIdx.x;           // 4 * 64 blocks, tile = 64 t
    int b = bid >> 6;
    int t0 = (bid & 63) * 64;
    __shared__ float lds[32][65];
    int tid = threadIdx.x;
    #pragma unroll
    for (int it = 0; it < 8; ++it) {
        int gi = it * 256 + tid;    // 0..2047
        int c = gi >> 6;
        int t = gi & 63;
        lds[c][t] = x[((size_t)b * IN_CH + c) * TSZ + t0 + t];
    }
    __syncthreads();
    #pragma unroll
    for (int it = 0; it < 4; ++it) {
        int wi = it * 256 + tid;    // dword index 0..1023
        int t  = wi >> 4;
        int cp = wi & 15;           // 2 channels per dword
        u32 b0 = f2bf(lds[cp * 2][t]);
        u32 b1 = f2bf(lds[cp * 2 + 1][t]);
        ((u32*)xT)[((size_t)b * TSZ + t0 + t) * 16 + cp] = b0 | (b1 << 16);
    }
}

// ---------------- main fused kernel ----------------------------------------
__global__ __launch_bounds__(512, 2)
void dconv_main(const u16* __restrict__ Wp, const float* __restrict__ bp,
                const u16* __restrict__ xT, float* __restrict__ out) {
    __shared__ u16 xs[XS_ROWS * XS_STRIDE];     // 10184 B, x tile [t][c]
    __shared__ u16 wslice[2][2][SLICE_U16];     // [buf][stream] 7168B each

    int tid  = threadIdx.x;
    int lane = tid & 63;
    int wave = tid >> 6;        // 0..7
    int wo   = wave & 1;        // o-parity stream
    int wt   = wave >> 1;       // col quarter (32 cols)
    int g    = lane >> 4;       // 0..3
    int col  = lane & 15;

    int bid = blockIdx.x;
    int b   = bid & 3;
    int tt  = (bid >> 2) & 31;
    int oh  = bid >> 7;         // o-half
    int t0  = tt * BLK_T;

    // ---- stage x tile: rows t0-3 .. t0+BLK_T+2, zero-padded ----
    #pragma unroll
    for (int it = 0; it < 5; ++it) {
        int wi = it * 512 + tid;            // dword index
        if (wi < XS_ROWS * 16) {
            int rr = wi >> 4;
            int cp = wi & 15;
            int t = t0 - 3 + rr;
            u32 v = 0;
            if (t >= 0 && t < TSZ)
                v = ((const u32*)xT)[((size_t)b * TSZ + t) * 16 + cp];
            *(u32*)&xs[rr * XS_STRIDE + cp * 2] = v;
        }
    }
    __syncthreads();

    // ---- prologue W stage: (cs=0, j=0) -> buf 0 ----
    {
        int o0 = oh * 16 + wo;
        int ch0 = o0 * 2;
        const u16* src = Wp + (size_t)(ch0 * 7 + 0) * SLICE_U16;
        u16* dst = &wslice[0][wo][0];
        if (wt < 3) {
            glds16(src + (2 * wt) * 512 + lane * 8, dst + (2 * wt) * 512);
            glds16(src + (2 * wt + 1) * 512 + lane * 8, dst + (2 * wt + 1) * 512);
        } else {
            glds16(src + 6 * 512 + lane * 8, dst + 6 * 512);
        }
    }

    // ---- per-tap B fragments, resident for the whole kernel ----
    // B[k=c][n=col] = x[b][c][t0 + colw + j - 3] = xs[colw + j][c], c = g*8..+7
    short8 bfrag[7][2];
    #pragma unroll
    for (int ct = 0; ct < 2; ++ct) {
        int colw = wt * 32 + ct * 16 + col;
        #pragma unroll
        for (int j = 0; j < 7; ++j) {
            const u32* px = (const u32*)&xs[(colw + j) * XS_STRIDE + g * 8];
            union { short8 s; u32 u[4]; } u8;
            u8.u[0] = px[0]; u8.u[1] = px[1]; u8.u[2] = px[2]; u8.u[3] = px[3];
            bfrag[j][ct] = u8.s;
        }
    }

    f32x4 acc[7][2];
    float yacc0 = 0.f, yacc1 = 0.f;
    int cur = 0;

    #pragma unroll 1
    for (int cs = 0; cs < 16; ++cs) {
        int s = cs >> 1, cc = cs & 1;
        int o = oh * 16 + wo + 2 * s;
        int ch = o * 2 + cc;

        // bias -> accumulator init (acc reg r maps to row p = g*4+r, m = tap k)
        const float* bsrc = bp + ch * 112 + g * 4;
        #pragma unroll
        for (int m = 0; m < 7; ++m) {
            f32x4 bv = *(const f32x4*)(bsrc + m * 16);
            acc[m][0] = bv; acc[m][1] = bv;
        }

        #pragma unroll
        for (int j = 0; j < 7; ++j) {
            __syncthreads();   // wslice[cur][wo] staged; prior reads drained
            int ns = cs * 7 + j + 1;
            if (ns < 112) {    // stage next j-slice into other buffer
                int ncs = ns / 7, nj = ns - ncs * 7;
                int nch = (oh * 16 + wo + 2 * (ncs >> 1)) * 2 + (ncs & 1);
                const u16* src = Wp + (size_t)(nch * 7 + nj) * SLICE_U16;
                u16* dst = &wslice[cur ^ 1][wo][0];
                if (wt < 3) {
                    glds16(src + (2 * wt) * 512 + lane * 8, dst + (2 * wt) * 512);
                    glds16(src + (2 * wt + 1) * 512 + lane * 8, dst + (2 * wt + 1) * 512);
                } else {
                    glds16(src + 6 * 512 + lane * 8, dst + 6 * 512);
                }
            }
            const u16* wl = &wslice[cur][wo][0];
            #pragma unroll
            for (int m = 0; m < 7; ++m) {
                // A[row = m*16 + col][c = g*8..+7], 16B aligned, lane-linear 1KB
                short8 af = *(const short8*)(wl + (m * 16 + col) * 32 + g * 8);
                acc[m][0] = __builtin_amdgcn_mfma_f32_16x16x32_bf16(af, bfrag[j][0], acc[m][0], 0, 0, 0);
                acc[m][1] = __builtin_amdgcn_mfma_f32_16x16x32_bf16(af, bfrag[j][1], acc[m][1], 0, 0, 0);
            }
            cur ^= 1;
        }

        // ---- softmax over k (= m, lane-local) + einsum contribution ----
        int ibase = cc * 16 + g * 4;   // i for reg r is ibase + r  (never wraps)
        #pragma unroll
        for (int ct = 0; ct < 2; ++ct) {
            int colw = wt * 32 + ct * 16 + col;
            u32 xv0[7], xv1[7];        // x[b][ibase..+3][t0+colw+k-3] as 2 dwords
            #pragma unroll
            for (int k = 0; k < 7; ++k) {
                const u32* px = (const u32*)&xs[(colw + k) * XS_STRIDE + ibase];
                xv0[k] = px[0]; xv1[k] = px[1];
            }
            #pragma unroll
            for (int r = 0; r < 4; ++r) {
                float mx = acc[0][ct][r];
                #pragma unroll
                for (int k = 1; k < 7; ++k) mx = fmaxf(mx, acc[k][ct][r]);
                float ssum = 0.f, psum = 0.f;
                #pragma unroll
                for (int k = 0; k < 7; ++k) {
                    float e = exp2f((acc[k][ct][r] - mx) * CEXP2);
                    u32 w = (r & 2) ? xv1[k] : xv0[k];
                    float xf = __uint_as_float((r & 1) ? (w & 0xffff0000u) : (w << 16));
                    ssum += e;
                    psum = fmaf(e, xf, psum);
                }
                float contrib = psum * __builtin_amdgcn_rcpf(ssum);
                if (ct == 0) yacc0 += contrib; else yacc1 += contrib;
            }
        }

        if (cc == 1) {   // o finished: reduce over lane groups g, store
            float v0 = yacc0, v1 = yacc1;
            v0 += __shfl_xor(v0, 16, 64); v0 += __shfl_xor(v0, 32, 64);
            v1 += __shfl_xor(v1, 16, 64); v1 += __shfl_xor(v1, 32, 64);
            if (lane < 16) {
                float* yo = out + ((size_t)b * OUT_CH + o) * TSZ + t0 + wt * 32 + col;
                yo[0] = v0;
                yo[16] = v1;
            }
            yacc0 = 0.f; yacc1 = 0.f;
        }
    }
}

// ---------------------------------------------------------------------------
extern "C" void kernel_launch(void* const* d_in, const int* in_sizes, int n_in,
                              void* d_out, int out_size, void* d_ws, size_t ws_size,
                              hipStream_t stream) {
    const float* x    = (const float*)d_in[0];
    const float* W    = (const float*)d_in[1];
    const float* bias = (const float*)d_in[2];
    float* out = (float*)d_out;

    // workspace: Wp bf16 (3,211,264 B) | bp f32 (28,672 B) | xT bf16 (1,048,576 B)
    u16*   Wp = (u16*)d_ws;
    float* bp = (float*)((char*)d_ws + 3211264);
    u16*   xT = (u16*)((char*)d_ws + 3211264 + 28672);

    hipLaunchKernelGGL(wprep, dim3(6272), dim3(256), 0, stream, W, bias, Wp, bp);
    hipLaunchKernelGGL(xprep, dim3(BSZ * (TSZ / 64)), dim3(256), 0, stream, x, xT);
    hipLaunchKernelGGL(dconv_main, dim3(256), dim3(512), 0, stream, Wp, bp, xT, out);
}

// Round 2
// 122.259 us; speedup vs baseline: 1.4995x; 1.4995x over previous
//
#include <hip/hip_runtime.h>
#include <hip/hip_bf16.h>

// DynamicConv1D fused kernel for MI355X (gfx950) — round 2.
//
// Round-1 post-mortem: LDS-read-BW bound (A-fragments re-read with only 2-col
// reuse; 8-way bank conflicts on A reads; 112 barriers/block).
// Round-2 structure:
//   grid 256 = (b:4) x (t-tile:8, BLK_T=512) x (o-split:8 -> 4 o = 8 chunks).
//   8 waves, each owns 64 cols (Ncol=4 MFMA col-tiles) -> A-reuse x4.
//   Whole 50KB W-chunk double-buffered in LDS (2 barriers-ish per phase -> 8
//   phases/block). A-fragment 16B-group XOR swizzle baked into Wp layout
//   (conflict-free reads; LDS dest stays linear for global_load_lds).
//   Softmax: no max-subtraction (args bounded), lane-local over taps.

typedef unsigned short u16;
typedef unsigned int u32;
typedef __attribute__((ext_vector_type(8))) short short8;
typedef __attribute__((ext_vector_type(4))) float f32x4;

#define IN_CH 32
#define OUT_CH 32
#define KW 7
#define TSZ 4096
#define BSZ 4
#define CONTR 224          // IN_CH*KW
#define NROWS 7168         // OUT_CH*IN_CH*KW
#define BLK_T 512
#define XS_STRIDE 40       // u16 per xs row (80B: 8B-aligned, 5col+g bank spread)
#define XS_ROWS (BLK_T + 6)   // 518
#define SLICE_U16 3584     // one (ch,j) slice: 112 rows * 32 c
#define CH_U16 25088       // one chunk: 7 slices
#define CEXP2 0.54528747f  // log2(e)/sqrt(7)

__device__ __forceinline__ u32 f2bf(float v) {   // f32 -> bf16 bits (RNE)
    u32 b = __float_as_uint(v);
    return (b + 0x7fffu + ((b >> 16) & 1u)) >> 16;
}

__device__ __forceinline__ void glds16(const u16* g, u16* l) {
    // 16B per lane; LDS dest = wave-uniform base (HW adds lane*16)
    __builtin_amdgcn_global_load_lds((__attribute__((address_space(1))) void*)g,
                                     (__attribute__((address_space(3))) void*)l,
                                     16, 0, 0);
}

// ---------------- prep 1: W permute + bf16 + group-swizzle, bias permute ----
// Wp u16 idx = ch*25088 + j*3584 + r'*32 + p'*8 + e,  r' = k*16 + q (tap-major)
// stored group p' holds source group p = p' ^ ((r'>>1)&3)  (c = p*8 + e)
__global__ __launch_bounds__(256)
void wprep(const float* __restrict__ W, const float* __restrict__ bias,
           u16* __restrict__ Wp, float* __restrict__ bp) {
    int idx = blockIdx.x * 256 + threadIdx.x;
    if (idx < NROWS * CONTR) {
        int e  = idx & 7;
        int pp = (idx >> 3) & 3;
        int t1 = idx >> 5;          // (ch*7+j)*112 + r'
        int rp = t1 % 112;
        int t2 = t1 / 112;
        int j  = t2 % 7;
        int ch = t2 / 7;
        int p  = pp ^ ((rp >> 1) & 3);
        int c  = p * 8 + e;
        int k  = rp >> 4;
        int q  = rp & 15;
        int gp = ch * 16 + q;       // = o*32 + i
        int o  = gp >> 5;
        int i  = gp & 31;
        int grow = (o * IN_CH + i) * KW + k;
        Wp[idx] = (u16)f2bf(W[(size_t)grow * CONTR + c * KW + j]);
    }
    if (idx < NROWS) {
        int rp = idx % 112;
        int ch = idx / 112;
        int k = rp >> 4, q = rp & 15;
        int gp = ch * 16 + q;
        int o = gp >> 5, i = gp & 31;
        bp[idx] = bias[(o * IN_CH + i) * KW + k];
    }
}

// ---------------- prep 2: x -> xT bf16 [b][t][c] ---------------------------
__global__ __launch_bounds__(256)
void xprep(const float* __restrict__ x, u16* __restrict__ xT) {
    int bid = blockIdx.x;
    int b = bid >> 6;
    int t0 = (bid & 63) * 64;
    __shared__ float lds[32][65];
    int tid = threadIdx.x;
    #pragma unroll
    for (int it = 0; it < 8; ++it) {
        int gi = it * 256 + tid;
        int c = gi >> 6;
        int t = gi & 63;
        lds[c][t] = x[((size_t)b * IN_CH + c) * TSZ + t0 + t];
    }
    __syncthreads();
    #pragma unroll
    for (int it = 0; it < 4; ++it) {
        int wi = it * 256 + tid;
        int t  = wi >> 4;
        int cp = wi & 15;
        u32 b0 = f2bf(lds[cp * 2][t]);
        u32 b1 = f2bf(lds[cp * 2 + 1][t]);
        ((u32*)xT)[((size_t)b * TSZ + t0 + t) * 16 + cp] = b0 | (b1 << 16);
    }
}

// ---------------- main fused kernel ----------------------------------------
__global__ __launch_bounds__(512, 1)
void dconv_main(const u16* __restrict__ Wp, const float* __restrict__ bp,
                const u16* __restrict__ xT, float* __restrict__ out) {
    __shared__ u16 xs[XS_ROWS * XS_STRIDE];   // 41,440 B: x tile [t][c]
    __shared__ u16 wbuf[2][CH_U16];           // 100,352 B: chunk double-buffer

    int tid  = threadIdx.x;
    int lane = tid & 63;
    int wave = tid >> 6;        // 0..7, owns cols wave*64 .. +63
    int g    = lane >> 4;       // 0..3
    int col  = lane & 15;

    int bid = blockIdx.x;
    int b   = bid & 3;
    int tt  = (bid >> 2) & 7;
    int os  = bid >> 5;         // o-split: chunks os*8 .. os*8+7
    int t0  = tt * BLK_T;

    // ---- stage x tile (rows t0-3 .. t0+BLK_T+2, zero-padded) ----
    #pragma unroll
    for (int it = 0; it < 17; ++it) {
        int wi = it * 512 + tid;            // dword (c-pair) index
        if (wi < XS_ROWS * 16) {
            int row = wi >> 4;
            int cp  = wi & 15;
            int t = t0 - 3 + row;
            u32 v = 0;
            if (t >= 0 && t < TSZ)
                v = ((const u32*)xT)[((size_t)b * TSZ + t) * 16 + cp];
            *(u32*)&xs[row * XS_STRIDE + cp * 2] = v;
        }
    }

    // ---- prologue: stage chunk 0 (wave w stages slice j=w) ----
    if (wave < 7) {
        const u16* src = Wp + (size_t)(os * 8) * CH_U16 + wave * SLICE_U16 + lane * 8;
        u16* dst = &wbuf[0][wave * SLICE_U16];
        #pragma unroll
        for (int it = 0; it < 7; ++it) glds16(src + it * 512, dst + it * 512);
    }
    __syncthreads();

    // lane-invariant A-read offset (undoes the Wp group swizzle)
    int laneA = col * 32 + ((g ^ ((col >> 1) & 3)) * 8);
    int colw0 = wave * 64 + col;

    float yacc[4] = {0.f, 0.f, 0.f, 0.f};

    #pragma unroll 1
    for (int ci = 0; ci < 8; ++ci) {
        int cur = ci & 1;
        // stage next chunk into the other buffer (hidden under compute)
        if (ci < 7 && wave < 7) {
            const u16* src = Wp + (size_t)(os * 8 + ci + 1) * CH_U16 + wave * SLICE_U16 + lane * 8;
            u16* dst = &wbuf[cur ^ 1][wave * SLICE_U16];
            #pragma unroll
            for (int it = 0; it < 7; ++it) glds16(src + it * 512, dst + it * 512);
        }

        int ch = os * 8 + ci;
        int cc = ci & 1;

        // bias -> accumulator init (acc reg r maps to row q = g*4+r, m = tap)
        f32x4 acc[7][4];
        const float* bsrc = bp + ch * 112 + g * 4;
        #pragma unroll
        for (int m = 0; m < 7; ++m) {
            f32x4 bv = *(const f32x4*)(bsrc + m * 16);
            acc[m][0] = bv; acc[m][1] = bv; acc[m][2] = bv; acc[m][3] = bv;
        }

        const u16* wl = &wbuf[cur][laneA];
        #pragma unroll
        for (int j = 0; j < 7; ++j) {
            // B fragments for this j (4 col-tiles), from xs
            short8 bf[4];
            #pragma unroll
            for (int ct = 0; ct < 4; ++ct)
                bf[ct] = *(const short8*)&xs[(colw0 + ct * 16 + j) * XS_STRIDE + g * 8];
            #pragma unroll
            for (int m = 0; m < 7; ++m) {
                short8 af = *(const short8*)(wl + j * SLICE_U16 + m * 512);
                acc[m][0] = __builtin_amdgcn_mfma_f32_16x16x32_bf16(af, bf[0], acc[m][0], 0, 0, 0);
                acc[m][1] = __builtin_amdgcn_mfma_f32_16x16x32_bf16(af, bf[1], acc[m][1], 0, 0, 0);
                acc[m][2] = __builtin_amdgcn_mfma_f32_16x16x32_bf16(af, bf[2], acc[m][2], 0, 0, 0);
                acc[m][3] = __builtin_amdgcn_mfma_f32_16x16x32_bf16(af, bf[3], acc[m][3], 0, 0, 0);
            }
        }

        // ---- softmax over taps (lane-local) + einsum contribution ----
        int ibase = cc * 16 + g * 4;        // i for reg r is ibase + r
        #pragma unroll
        for (int ct = 0; ct < 4; ++ct) {
            int colw = colw0 + ct * 16;
            u32 xv0[7], xv1[7];             // x[b][ibase..+3][t+k-3] (2 dwords)
            #pragma unroll
            for (int k = 0; k < 7; ++k) {
                const u32* px = (const u32*)&xs[(colw + k) * XS_STRIDE + ibase];
                xv0[k] = px[0]; xv1[k] = px[1];
            }
            #pragma unroll
            for (int r = 0; r < 4; ++r) {
                float ssum = 0.f, psum = 0.f;
                #pragma unroll
                for (int k = 0; k < 7; ++k) {
                    // |dw/sqrt7| small -> safe without max subtraction
                    float e = __builtin_amdgcn_exp2f(acc[k][ct][r] * CEXP2);
                    u32 w = (r & 2) ? xv1[k] : xv0[k];
                    float xf = __uint_as_float((r & 1) ? (w & 0xffff0000u) : (w << 16));
                    ssum += e;
                    psum = fmaf(e, xf, psum);
                }
                yacc[ct] += psum * __builtin_amdgcn_rcpf(ssum);
            }
        }

        if (cc == 1) {      // o complete: reduce over lane-groups g, store
            int o = os * 4 + (ci >> 1);
            #pragma unroll
            for (int ct = 0; ct < 4; ++ct) {
                float v = yacc[ct];
                v += __shfl_xor(v, 16, 64);
                v += __shfl_xor(v, 32, 64);
                if (lane < 16)
                    out[((size_t)b * OUT_CH + o) * TSZ + t0 + wave * 64 + ct * 16 + col] = v;
                yacc[ct] = 0.f;
            }
        }
        __syncthreads();    // staged chunk visible; reads of wbuf[cur] done
    }
}

// ---------------------------------------------------------------------------
extern "C" void kernel_launch(void* const* d_in, const int* in_sizes, int n_in,
                              void* d_out, int out_size, void* d_ws, size_t ws_size,
                              hipStream_t stream) {
    const float* x    = (const float*)d_in[0];
    const float* W    = (const float*)d_in[1];
    const float* bias = (const float*)d_in[2];
    float* out = (float*)d_out;

    // workspace: Wp bf16 (3,211,264 B) | bp f32 (28,672 B) | xT bf16 (1,048,576 B)
    u16*   Wp = (u16*)d_ws;
    float* bp = (float*)((char*)d_ws + 3211264);
    u16*   xT = (u16*)((char*)d_ws + 3211264 + 28672);

    hipLaunchKernelGGL(wprep, dim3(6272), dim3(256), 0, stream, W, bias, Wp, bp);
    hipLaunchKernelGGL(xprep, dim3(BSZ * (TSZ / 64)), dim3(256), 0, stream, x, xT);
    hipLaunchKernelGGL(dconv_main, dim3(256), dim3(512), 0, stream, Wp, bp, xT, out);
}